// Round 2
// baseline (22263.028 us; speedup 1.0000x reference)
//
#include <hip/hip_runtime.h>
#include <hip/hip_bf16.h>

#define B_ 8
#define T_ 16
#define S_ 257
#define D_ 512
#define FFN_ 2048
#define NH_ 8
#define HD_ 64
#define PTD_ 192
#define NTOK (B_*T_*S_)        // 32896
#define NFRAME (B_*T_)         // 128
#define CHROWS 4112            // 16 frames * 257  ==  T_ * S_ (temporal per-b chunk)

__device__ __forceinline__ float warp_rsum(float v){
#pragma unroll
  for (int m = 32; m >= 1; m >>= 1) v += __shfl_xor(v, m);
  return v;
}
__device__ __forceinline__ float warp_rmax(float v){
#pragma unroll
  for (int m = 32; m >= 1; m >>= 1) v = fmaxf(v, __shfl_xor(v, m));
  return v;
}
__device__ __forceinline__ float gelu_f(float x){
  float x3 = x*x*x;
  return 0.5f*x*(1.0f + tanhf(0.7978845608028654f*(x + 0.044715f*x3)));
}

// ---------------- patchify: videos (B,T,128,128,3) + action token -> x (B,T,257,192)
__global__ __launch_bounds__(256) void patchify_kernel(
    const float* __restrict__ videos, const float* __restrict__ action_token,
    float* __restrict__ x)
{
  int idx = blockIdx.x * 256 + threadIdx.x;
  const int total = NTOK * PTD_;
  if (idx >= total) return;
  int e  = idx % PTD_;
  int s  = (idx / PTD_) % S_;
  int bt = idx / (PTD_ * S_);
  float v;
  if (s == 0) {
    v = action_token[e];
  } else {
    int p = s - 1, ph = p >> 4, pw = p & 15;
    int i = e / 24, r = e % 24, j = r / 3, c = r % 3;
    int row = ph * 8 + i, col = pw * 8 + j;
    v = videos[(((long)bt * 128 + row) * 128 + col) * 3 + c];
  }
  x[idx] = v;
}

// ---------------- per-row LN stats: mean, rstd  (rows of 512)
__global__ __launch_bounds__(256) void ln_stats(
    const float* __restrict__ x, float* __restrict__ stats)
{
  int row = blockIdx.x * 4 + (threadIdx.x >> 6);
  int lane = threadIdx.x & 63;
  const float* xr = x + (long)row * D_;
  float4 u0 = *(const float4*)(xr + lane * 8);
  float4 u1 = *(const float4*)(xr + lane * 8 + 4);
  float s = u0.x + u0.y + u0.z + u0.w + u1.x + u1.y + u1.z + u1.w;
  s = warp_rsum(s);
  float mean = s * (1.0f / 512.0f);
  float d[8] = {u0.x - mean, u0.y - mean, u0.z - mean, u0.w - mean,
                u1.x - mean, u1.y - mean, u1.z - mean, u1.w - mean};
  float ss = 0.f;
#pragma unroll
  for (int i = 0; i < 8; i++) ss = fmaf(d[i], d[i], ss);
  ss = warp_rsum(ss);
  float rstd = rsqrtf(ss * (1.0f / 512.0f) + 1e-5f);
  if (lane == 0) { stats[2 * (long)row] = mean; stats[2 * (long)row + 1] = rstd; }
}

// ---------------- generic fp32 GEMM: C[M,N] (=|+=) act(A[M,K]@B[K,N] (+bias))
// 64x64x16 tiles, 256 threads, 4x4 microtile, transposed A-tile in LDS, M-guarded.
template<bool BIAS, bool GELU, bool RESID>
__global__ __launch_bounds__(256) void gemm_main(
    const float* __restrict__ A, const float* __restrict__ Bm,
    const float* __restrict__ bias, float* __restrict__ C,
    int M, int N, int K)
{
  __shared__ __align__(16) float Ast[16][68];
  __shared__ __align__(16) float Bs[16][64];
  const int tid = threadIdx.x;
  const int tx = tid & 15, ty = tid >> 4;
  const int m0 = blockIdx.x << 6, n0 = blockIdx.y << 6;
  const int lr = tid >> 2, lc = (tid & 3) << 2;   // A loader: row 0..63, col 0..12
  const int br = tid >> 4, bc = (tid & 15) << 2;  // B loader: row 0..15, col 0..60
  const int arow = m0 + lr;
  float acc[4][4] = {};
  const float* Aptr = A + (long)arow * K + lc;
  const float* Bptr = Bm + (long)br * N + n0 + bc;
  for (int k0 = 0; k0 < K; k0 += 16) {
    float4 av = make_float4(0.f, 0.f, 0.f, 0.f);
    if (arow < M) av = *(const float4*)(Aptr + k0);
    float4 bv = *(const float4*)(Bptr + (long)k0 * N);
    Ast[lc+0][lr] = av.x; Ast[lc+1][lr] = av.y; Ast[lc+2][lr] = av.z; Ast[lc+3][lr] = av.w;
    *(float4*)&Bs[br][bc] = bv;
    __syncthreads();
#pragma unroll
    for (int kk = 0; kk < 16; kk++) {
      const float4 a4 = *(const float4*)&Ast[kk][ty << 2];
      const float4 b4 = *(const float4*)&Bs[kk][tx << 2];
      const float a_[4] = {a4.x, a4.y, a4.z, a4.w};
      const float b_[4] = {b4.x, b4.y, b4.z, b4.w};
#pragma unroll
      for (int i = 0; i < 4; i++)
#pragma unroll
        for (int j = 0; j < 4; j++)
          acc[i][j] = fmaf(a_[i], b_[j], acc[i][j]);
    }
    __syncthreads();
  }
#pragma unroll
  for (int i = 0; i < 4; i++) {
    int m = m0 + (ty << 2) + i;
    if (m >= M) continue;
#pragma unroll
    for (int j = 0; j < 4; j++) {
      int n = n0 + (tx << 2) + j;
      float v = acc[i][j];
      if (BIAS) v += bias[n];
      if (GELU) v = gelu_f(v);
      long idx = (long)m * N + n;
      if (RESID) C[idx] += v; else C[idx] = v;
    }
  }
}

// ---------------- LN-fused GEMM: C = act(LN(A)@B (+bias)); LN via precomputed stats
template<bool BIAS, bool GELU>
__global__ __launch_bounds__(256) void gemm_ln(
    const float* __restrict__ A, const float* __restrict__ stats,
    const float* __restrict__ g, const float* __restrict__ be,
    const float* __restrict__ Bm, const float* __restrict__ bias,
    float* __restrict__ C, int M, int N, int K)
{
  __shared__ __align__(16) float Ast[16][68];
  __shared__ __align__(16) float Bs[16][64];
  const int tid = threadIdx.x;
  const int tx = tid & 15, ty = tid >> 4;
  const int m0 = blockIdx.x << 6, n0 = blockIdx.y << 6;
  const int lr = tid >> 2, lc = (tid & 3) << 2;
  const int br = tid >> 4, bc = (tid & 15) << 2;
  const int arow = m0 + lr;
  float mean = 0.f, rstd = 0.f;
  if (arow < M) { mean = stats[2 * (long)arow]; rstd = stats[2 * (long)arow + 1]; }
  float acc[4][4] = {};
  const float* Aptr = A + (long)arow * K + lc;
  const float* Bptr = Bm + (long)br * N + n0 + bc;
  for (int k0 = 0; k0 < K; k0 += 16) {
    float4 av = make_float4(0.f, 0.f, 0.f, 0.f);
    if (arow < M) av = *(const float4*)(Aptr + k0);
    float4 g4 = *(const float4*)(g + k0 + lc);
    float4 b4 = *(const float4*)(be + k0 + lc);
    float4 bv = *(const float4*)(Bptr + (long)k0 * N);
    Ast[lc+0][lr] = (av.x - mean) * rstd * g4.x + b4.x;
    Ast[lc+1][lr] = (av.y - mean) * rstd * g4.y + b4.y;
    Ast[lc+2][lr] = (av.z - mean) * rstd * g4.z + b4.z;
    Ast[lc+3][lr] = (av.w - mean) * rstd * g4.w + b4.w;
    *(float4*)&Bs[br][bc] = bv;
    __syncthreads();
#pragma unroll
    for (int kk = 0; kk < 16; kk++) {
      const float4 a4 = *(const float4*)&Ast[kk][ty << 2];
      const float4 b4 = *(const float4*)&Bs[kk][tx << 2];
      const float a_[4] = {a4.x, a4.y, a4.z, a4.w};
      const float b_[4] = {b4.x, b4.y, b4.z, b4.w};
#pragma unroll
      for (int i = 0; i < 4; i++)
#pragma unroll
        for (int j = 0; j < 4; j++)
          acc[i][j] = fmaf(a_[i], b_[j], acc[i][j]);
    }
    __syncthreads();
  }
#pragma unroll
  for (int i = 0; i < 4; i++) {
    int m = m0 + (ty << 2) + i;
    if (m >= M) continue;
#pragma unroll
    for (int j = 0; j < 4; j++) {
      int n = n0 + (tx << 2) + j;
      float v = acc[i][j];
      if (BIAS) v += bias[n];
      if (GELU) v = gelu_f(v);
      long idx = (long)m * N + n;
      C[idx] = v;
    }
  }
}

// ---------------- spatial attention scores for one 16-frame chunk (128 f*h pairs)
// qkvc: [4112][1536] chunk-local rows.  scores: [128][257][257]
__global__ __launch_bounds__(256) void spatial_scores(
    const float* __restrict__ qkvc, float* __restrict__ scores)
{
  const int z = blockIdx.z;               // local (frame,head): 0..127
  const int fl = z >> 3, hh = z & 7;
  const float* Q  = qkvc + (long)fl * S_ * 1536 + hh * HD_;
  const float* Kp = Q + 512;
  float* C = scores + (long)z * S_ * S_;
  const int m0 = blockIdx.x << 6, n0 = blockIdx.y << 6;
  __shared__ __align__(16) float Qs[16][68];
  __shared__ __align__(16) float Ks[16][68];
  const int tid = threadIdx.x, tx = tid & 15, ty = tid >> 4;
  const int lr = tid >> 2, lc = (tid & 3) << 2;
  float acc[4][4] = {};
  for (int k0 = 0; k0 < 64; k0 += 16) {
    float4 qv = make_float4(0,0,0,0), kv = make_float4(0,0,0,0);
    if (m0 + lr < S_) qv = *(const float4*)(Q  + (long)(m0 + lr) * 1536 + k0 + lc);
    if (n0 + lr < S_) kv = *(const float4*)(Kp + (long)(n0 + lr) * 1536 + k0 + lc);
    Qs[lc+0][lr]=qv.x; Qs[lc+1][lr]=qv.y; Qs[lc+2][lr]=qv.z; Qs[lc+3][lr]=qv.w;
    Ks[lc+0][lr]=kv.x; Ks[lc+1][lr]=kv.y; Ks[lc+2][lr]=kv.z; Ks[lc+3][lr]=kv.w;
    __syncthreads();
#pragma unroll
    for (int kk = 0; kk < 16; kk++) {
      const float4 a4 = *(const float4*)&Qs[kk][ty << 2];
      const float4 b4 = *(const float4*)&Ks[kk][tx << 2];
      const float a_[4] = {a4.x, a4.y, a4.z, a4.w};
      const float b_[4] = {b4.x, b4.y, b4.z, b4.w};
#pragma unroll
      for (int i = 0; i < 4; i++)
#pragma unroll
        for (int j = 0; j < 4; j++)
          acc[i][j] = fmaf(a_[i], b_[j], acc[i][j]);
    }
    __syncthreads();
  }
#pragma unroll
  for (int i = 0; i < 4; i++) {
    int m = m0 + (ty << 2) + i;
    if (m >= S_) continue;
#pragma unroll
    for (int j = 0; j < 4; j++) {
      int n = n0 + (tx << 2) + j;
      if (n < S_) C[(long)m * S_ + n] = acc[i][j] * 0.125f;
    }
  }
}

__global__ __launch_bounds__(256) void softmax_rows(float* __restrict__ sc)
{
  int row = blockIdx.x * 4 + (threadIdx.x >> 6);
  int lane = threadIdx.x & 63;
  float* p = sc + (long)row * S_;
  float v[5]; float mx = -3.0e38f;
#pragma unroll
  for (int j = 0; j < 5; j++) {
    int idx = lane + (j << 6);
    v[j] = (idx < S_) ? p[idx] : -3.0e38f;
    mx = fmaxf(mx, v[j]);
  }
  mx = warp_rmax(mx);
  float sum = 0.f;
#pragma unroll
  for (int j = 0; j < 5; j++) {
    int idx = lane + (j << 6);
    float e = (idx < S_) ? expf(v[j] - mx) : 0.f;
    v[j] = e; sum += e;
  }
  sum = warp_rsum(sum);
  float inv = 1.0f / sum;
#pragma unroll
  for (int j = 0; j < 5; j++) {
    int idx = lane + (j << 6);
    if (idx < S_) p[idx] = v[j] * inv;
  }
}

// ---------------- P@V for the chunk -> ctx_chunk [4112][512]
__global__ __launch_bounds__(256) void spatial_pv(
    const float* __restrict__ qkvc, const float* __restrict__ scores,
    float* __restrict__ ctxc)
{
  const int z = blockIdx.z;
  const int fl = z >> 3, hh = z & 7;
  const float* P = scores + (long)z * S_ * S_;
  const float* V = qkvc + (long)fl * S_ * 1536 + 1024 + hh * HD_;
  float* C = ctxc + (long)fl * S_ * D_ + hh * HD_;
  const int m0 = blockIdx.x << 6;
  __shared__ __align__(16) float Ps[16][68];
  __shared__ __align__(16) float Vs[16][64];
  const int tid = threadIdx.x, tx = tid & 15, ty = tid >> 4;
  const int lr = tid >> 2, lc = (tid & 3) << 2;
  const int br = tid >> 4, bc = (tid & 15) << 2;
  float acc[4][4] = {};
  for (int k0 = 0; k0 < S_; k0 += 16) {
#pragma unroll
    for (int e = 0; e < 4; e++) {
      int kcol = k0 + lc + e;
      Ps[lc+e][lr] = (m0 + lr < S_ && kcol < S_) ? P[(long)(m0 + lr) * S_ + kcol] : 0.f;
    }
    int vr = k0 + br;
    float4 vv = make_float4(0,0,0,0);
    if (vr < S_) vv = *(const float4*)(V + (long)vr * 1536 + bc);
    *(float4*)&Vs[br][bc] = vv;
    __syncthreads();
#pragma unroll
    for (int kk = 0; kk < 16; kk++) {
      const float4 a4 = *(const float4*)&Ps[kk][ty << 2];
      const float4 b4 = *(const float4*)&Vs[kk][tx << 2];
      const float a_[4] = {a4.x, a4.y, a4.z, a4.w};
      const float b_[4] = {b4.x, b4.y, b4.z, b4.w};
#pragma unroll
      for (int i = 0; i < 4; i++)
#pragma unroll
        for (int j = 0; j < 4; j++)
          acc[i][j] = fmaf(a_[i], b_[j], acc[i][j]);
    }
    __syncthreads();
  }
#pragma unroll
  for (int i = 0; i < 4; i++) {
    int m = m0 + (ty << 2) + i;
    if (m >= S_) continue;
#pragma unroll
    for (int j = 0; j < 4; j++) {
      int n = (tx << 2) + j;
      C[(long)m * D_ + n] = acc[i][j];
    }
  }
}

// ---------------- temporal causal attention for one batch b (chunk-local qkv)
// qkvc rows: t*257+s ; ctxc rows: t*257+s. One wave per (s, head).
__global__ __launch_bounds__(64) void temporal_attn(
    const float* __restrict__ qkvc, float* __restrict__ ctxc)
{
  const int gid = blockIdx.x;           // s*8+h, 0..2055
  const int hh = gid & 7;
  const int s = gid >> 3;
  const int lane = threadIdx.x;
  __shared__ float Qs[16][65];
  __shared__ float Ks[16][65];
  __shared__ float Pm[16][17];
  float v[16];
  const long base = (long)s * 1536 + hh * HD_ + lane;
  const long tstr = (long)S_ * 1536;
#pragma unroll
  for (int t = 0; t < 16; t++) {
    long r = base + t * tstr;
    Qs[t][lane] = qkvc[r];
    Ks[t][lane] = qkvc[r + 512];
    v[t] = qkvc[r + 1024];
  }
  __syncthreads();
  const int rq = lane >> 2, c0 = lane & 3;
  float sc[4];
#pragma unroll
  for (int j = 0; j < 4; j++) {
    int c = c0 + (j << 2);
    if (c <= rq) {
      float d = 0.f;
#pragma unroll
      for (int k = 0; k < 64; k++) d = fmaf(Qs[rq][k], Ks[c][k], d);
      sc[j] = d * 0.125f;
    } else sc[j] = -3.0e38f;
  }
  float mx = fmaxf(fmaxf(sc[0], sc[1]), fmaxf(sc[2], sc[3]));
  mx = fmaxf(mx, __shfl_xor(mx, 1));
  mx = fmaxf(mx, __shfl_xor(mx, 2));
  float sum = 0.f;
#pragma unroll
  for (int j = 0; j < 4; j++) { sc[j] = expf(sc[j] - mx); sum += sc[j]; }
  sum += __shfl_xor(sum, 1);
  sum += __shfl_xor(sum, 2);
  float inv = 1.0f / sum;
#pragma unroll
  for (int j = 0; j < 4; j++) Pm[rq][c0 + (j << 2)] = sc[j] * inv;
  __syncthreads();
#pragma unroll
  for (int t = 0; t < 16; t++) {
    float o = 0.f;
#pragma unroll
    for (int k = 0; k < 16; k++) o = fmaf(Pm[t][k], v[k], o);
    ctxc[((long)t * S_ + s) * D_ + hh * HD_ + lane] = o;
  }
}

// ---------------- final LN + projection + VQ argmin + action head
__global__ __launch_bounds__(256) void final_vq(
    const float* __restrict__ tok, const float* __restrict__ lnf_g,
    const float* __restrict__ lnf_b, const float* __restrict__ out_w,
    const float* __restrict__ codebook, const float* __restrict__ action_w,
    float* __restrict__ out)
{
  __shared__ float xs[512];
  __shared__ float red[256];
  __shared__ float zs[64];
  __shared__ float bd[256];
  __shared__ int   bi[256];
  const int b = blockIdx.x / 15, tm = blockIdx.x % 15;
  const int tid = threadIdx.x;
  const float* xr = tok + ((long)(b * T_ + tm + 1) * S_) * D_;   // s = 0
  xs[tid] = xr[tid]; xs[tid + 256] = xr[tid + 256];
  red[tid] = xs[tid] + xs[tid + 256];
  __syncthreads();
  for (int off = 128; off >= 1; off >>= 1) {
    if (tid < off) red[tid] += red[tid + off];
    __syncthreads();
  }
  float mean = red[0] * (1.0f / 512.0f);
  __syncthreads();
  float d0 = xs[tid] - mean, d1 = xs[tid + 256] - mean;
  red[tid] = d0 * d0 + d1 * d1;
  __syncthreads();
  for (int off = 128; off >= 1; off >>= 1) {
    if (tid < off) red[tid] += red[tid + off];
    __syncthreads();
  }
  float rs = rsqrtf(red[0] * (1.0f / 512.0f) + 1e-5f);
  __syncthreads();
  xs[tid]       = d0 * rs * lnf_g[tid]       + lnf_b[tid];
  xs[tid + 256] = d1 * rs * lnf_g[tid + 256] + lnf_b[tid + 256];
  __syncthreads();
  if (tid < 64) {
    float z = 0.f;
    for (int d = 0; d < 512; d++) z = fmaf(xs[d], out_w[d * 64 + tid], z);
    zs[tid] = z;
  }
  __syncthreads();
  float best = 3.0e38f; int bidx = 0;
  for (int c = tid; c < 4096; c += 256) {
    const float* cp = codebook + (long)c * 64;
    float dot = 0.f, cn = 0.f;
#pragma unroll 8
    for (int k = 0; k < 64; k++) { float w = cp[k]; dot = fmaf(zs[k], w, dot); cn = fmaf(w, w, cn); }
    float dist = cn - 2.0f * dot;
    if (dist < best) { best = dist; bidx = c; }
  }
  bd[tid] = best; bi[tid] = bidx;
  __syncthreads();
  for (int off = 128; off >= 1; off >>= 1) {
    if (tid < off) {
      if (bd[tid + off] < bd[tid] || (bd[tid + off] == bd[tid] && bi[tid + off] < bi[tid])) {
        bd[tid] = bd[tid + off]; bi[tid] = bi[tid + off];
      }
    }
    __syncthreads();
  }
  int idx = bi[0];
  if (tid < 16) {
    const float* cp = codebook + (long)idx * 64;
    float o = 0.f;
#pragma unroll
    for (int k = 0; k < 64; k++) o = fmaf(cp[k], action_w[k * 16 + tid], o);
    out[((long)(b * 15 + tm)) * 16 + tid] = o;
  }
}

extern "C" void kernel_launch(void* const* d_in, const int* in_sizes, int n_in,
                              void* d_out, int out_size, void* d_ws, size_t ws_size,
                              hipStream_t stream)
{
  const float* videos       = (const float*)d_in[0];
  const float* patch_w      = (const float*)d_in[1];
  const float* patch_b      = (const float*)d_in[2];
  const float* action_token = (const float*)d_in[3];
  const float* ln1_g  = (const float*)d_in[4];
  const float* ln1_b  = (const float*)d_in[5];
  const float* wqkv_s = (const float*)d_in[6];
  const float* wo_s   = (const float*)d_in[7];
  const float* ln2_g  = (const float*)d_in[8];
  const float* ln2_b  = (const float*)d_in[9];
  const float* wqkv_t = (const float*)d_in[10];
  const float* wo_t   = (const float*)d_in[11];
  const float* ln3_g  = (const float*)d_in[12];
  const float* ln3_b  = (const float*)d_in[13];
  const float* mlp_w1 = (const float*)d_in[14];
  const float* mlp_b1 = (const float*)d_in[15];
  const float* mlp_w2 = (const float*)d_in[16];
  const float* mlp_b2 = (const float*)d_in[17];
  const float* lnf_g  = (const float*)d_in[18];
  const float* lnf_b  = (const float*)d_in[19];
  const float* out_w  = (const float*)d_in[20];
  const float* codebook = (const float*)d_in[21];
  const float* action_w = (const float*)d_in[22];
  float* out = (float*)d_out;

  // ---- workspace layout (floats), total ~135.1 MB
  float* ws    = (float*)d_ws;
  float* tok   = ws;                                  // 16,842,752
  float* stats = tok + (long)NTOK * D_;               //     65,792
  float* qkvc  = stats + (long)NTOK * 2;              //  6,316,032  (4112 x 1536)
  float* ctxc  = qkvc + (long)CHROWS * 1536;          //  2,105,344  (4112 x 512)
  float* scratch = ctxc + (long)CHROWS * D_;          //  8,454,272  (scores / mlp-mid / x_patch)

  // patchify + embed (x_patch = 6,316,032 floats fits in scratch)
  patchify_kernel<<<(NTOK * PTD_) / 256, 256, 0, stream>>>(videos, action_token, scratch);
  gemm_main<true, false, false><<<dim3(NTOK / 64, D_ / 64), 256, 0, stream>>>(
      scratch, patch_w, patch_b, tok, NTOK, D_, PTD_);

  for (int L = 0; L < 4; L++) {
    const float* wqkv_si = wqkv_s + (long)L * 512 * 1536;
    const float* wo_si   = wo_s   + (long)L * 512 * 512;
    const float* wqkv_ti = wqkv_t + (long)L * 512 * 1536;
    const float* wo_ti   = wo_t   + (long)L * 512 * 512;

    // ---- spatial attention (8 chunks of 16 frames = 4112 rows each)
    ln_stats<<<NTOK / 4, 256, 0, stream>>>(tok, stats);
    for (int cb = 0; cb < 8; cb++) {
      long r0 = (long)cb * CHROWS;
      gemm_ln<false, false><<<dim3((CHROWS + 63) / 64, 1536 / 64), 256, 0, stream>>>(
          tok + r0 * D_, stats + r0 * 2, ln1_g + L * 512, ln1_b + L * 512,
          wqkv_si, nullptr, qkvc, CHROWS, 1536, D_);
      spatial_scores<<<dim3(5, 5, 128), 256, 0, stream>>>(qkvc, scratch);
      softmax_rows<<<(128 * S_) / 4, 256, 0, stream>>>(scratch);
      spatial_pv<<<dim3(5, 1, 128), 256, 0, stream>>>(qkvc, scratch, ctxc);
      gemm_main<false, false, true><<<dim3((CHROWS + 63) / 64, D_ / 64), 256, 0, stream>>>(
          ctxc, wo_si, nullptr, tok + r0 * D_, CHROWS, D_, D_);
    }

    // ---- temporal attention (8 chunks: one batch b = 4112 rows each)
    ln_stats<<<NTOK / 4, 256, 0, stream>>>(tok, stats);
    for (int b = 0; b < 8; b++) {
      long r0 = (long)b * CHROWS;
      gemm_ln<false, false><<<dim3((CHROWS + 63) / 64, 1536 / 64), 256, 0, stream>>>(
          tok + r0 * D_, stats + r0 * 2, ln2_g + L * 512, ln2_b + L * 512,
          wqkv_ti, nullptr, qkvc, CHROWS, 1536, D_);
      temporal_attn<<<S_ * NH_, 64, 0, stream>>>(qkvc, ctxc);
      gemm_main<false, false, true><<<dim3((CHROWS + 63) / 64, D_ / 64), 256, 0, stream>>>(
          ctxc, wo_ti, nullptr, tok + r0 * D_, CHROWS, D_, D_);
    }

    // ---- MLP (chunks of 4096 rows; mid = 4096x2048 fits scratch)
    ln_stats<<<NTOK / 4, 256, 0, stream>>>(tok, stats);
    for (int c = 0; c < 9; c++) {
      long m0 = (long)c * 4096;
      int mr = NTOK - (int)m0; if (mr > 4096) mr = 4096;
      if (mr <= 0) break;
      gemm_ln<true, true><<<dim3((mr + 63) / 64, FFN_ / 64), 256, 0, stream>>>(
          tok + m0 * D_, stats + m0 * 2, ln3_g + L * 512, ln3_b + L * 512,
          mlp_w1 + (long)L * 512 * 2048, mlp_b1 + L * 2048,
          scratch, mr, FFN_, D_);
      gemm_main<true, false, true><<<dim3((mr + 63) / 64, D_ / 64), 256, 0, stream>>>(
          scratch, mlp_w2 + (long)L * 2048 * 512, mlp_b2 + L * 512,
          tok + m0 * D_, mr, D_, FFN_);
    }
  }

  final_vq<<<B_ * (T_ - 1), 256, 0, stream>>>(tok, lnf_g, lnf_b, out_w, codebook, action_w, out);
}

// Round 5
// 14453.134 us; speedup vs baseline: 1.5404x; 1.5404x over previous
//
#include <hip/hip_runtime.h>
#include <hip/hip_bf16.h>

#define B_ 8
#define T_ 16
#define S_ 257
#define D_ 512
#define FFN_ 2048
#define NH_ 8
#define HD_ 64
#define PTD_ 192
#define NTOK (B_*T_*S_)        // 32896
#define CH 4112                // 16 frames * 257 rows per chunk
#define WSCALE 64.0f
#define WINV 0.015625f

typedef unsigned int uint;
typedef unsigned short ushort;
typedef __attribute__((ext_vector_type(8))) _Float16 half8;
typedef __attribute__((ext_vector_type(4))) float f32x4;

__device__ __forceinline__ float warp_rsum(float v){
#pragma unroll
  for (int m = 32; m >= 1; m >>= 1) v += __shfl_xor(v, m);
  return v;
}
__device__ __forceinline__ float warp_rmax(float v){
#pragma unroll
  for (int m = 32; m >= 1; m >>= 1) v = fmaxf(v, __shfl_xor(v, m));
  return v;
}
__device__ __forceinline__ float gelu_f(float x){
  float x3 = x*x*x;
  return 0.5f*x*(1.0f + tanhf(0.7978845608028654f*(x + 0.044715f*x3)));
}
// split fp32 -> f16 hi + f16 lo (RNE).  x ~ hi + lo with ~2^-22 rel err (normal range).
__device__ __forceinline__ void split_f16(float f, ushort& h, ushort& l){
  _Float16 hh = (_Float16)f;
  float hf = (float)hh;
  _Float16 ll = (_Float16)(f - hf);
  h = __builtin_bit_cast(ushort, hh);
  l = __builtin_bit_cast(ushort, ll);
}

// ---------------- per-row LN stats: mean, rstd  (rows of 512)
__global__ __launch_bounds__(256) void ln_stats(
    const float* __restrict__ x, float* __restrict__ stats)
{
  int row = blockIdx.x * 4 + (threadIdx.x >> 6);
  int lane = threadIdx.x & 63;
  const float* xr = x + (long)row * D_;
  float4 u0 = *(const float4*)(xr + lane * 8);
  float4 u1 = *(const float4*)(xr + lane * 8 + 4);
  float s = u0.x + u0.y + u0.z + u0.w + u1.x + u1.y + u1.z + u1.w;
  s = warp_rsum(s);
  float mean = s * (1.0f / 512.0f);
  float d[8] = {u0.x - mean, u0.y - mean, u0.z - mean, u0.w - mean,
                u1.x - mean, u1.y - mean, u1.z - mean, u1.w - mean};
  float ss = 0.f;
#pragma unroll
  for (int i = 0; i < 8; i++) ss = fmaf(d[i], d[i], ss);
  ss = warp_rsum(ss);
  float rstd = rsqrtf(ss * (1.0f / 512.0f) + 1e-5f);
  if (lane == 0) { stats[2 * (long)row] = mean; stats[2 * (long)row + 1] = rstd; }
}

// ---------------- weight transpose + split:  W[K][N] f32 -> (W*64) as Whi[N][K], Wlo[N][K] f16
__global__ __launch_bounds__(256) void convert_w(
    const float* __restrict__ W, ushort* __restrict__ Whi, ushort* __restrict__ Wlo,
    int N, int K)
{
  __shared__ float Tt[64][65];
  const int tid = threadIdx.x;
  const int k0 = blockIdx.x << 6, n0 = blockIdx.y << 6;
  {
    int kk = tid >> 2, nb = (tid & 3) << 4;
#pragma unroll
    for (int q = 0; q < 4; q++) {
      float4 v = *(const float4*)(W + (long)(k0 + kk) * N + n0 + nb + 4 * q);
      Tt[kk][nb + 4*q + 0] = v.x; Tt[kk][nb + 4*q + 1] = v.y;
      Tt[kk][nb + 4*q + 2] = v.z; Tt[kk][nb + 4*q + 3] = v.w;
    }
  }
  __syncthreads();
  {
    int nn = tid >> 2, kb = (tid & 3) << 4;
    uint hw[8], lw[8];
#pragma unroll
    for (int q = 0; q < 8; q++) {
      float a = Tt[kb + 2*q][nn] * WSCALE, b = Tt[kb + 2*q + 1][nn] * WSCALE;
      ushort ha, la, hb, lb;
      split_f16(a, ha, la); split_f16(b, hb, lb);
      hw[q] = (uint)ha | ((uint)hb << 16); lw[q] = (uint)la | ((uint)lb << 16);
    }
    ushort* dh = Whi + (long)(n0 + nn) * K + k0 + kb;
    ushort* dl = Wlo + (long)(n0 + nn) * K + k0 + kb;
    ((uint4*)dh)[0] = make_uint4(hw[0], hw[1], hw[2], hw[3]);
    ((uint4*)dh)[1] = make_uint4(hw[4], hw[5], hw[6], hw[7]);
    ((uint4*)dl)[0] = make_uint4(lw[0], lw[1], lw[2], lw[3]);
    ((uint4*)dl)[1] = make_uint4(lw[4], lw[5], lw[6], lw[7]);
  }
}

// ---------------- split-f16 MFMA GEMM:  C[M][N] (=|+=) act((op(A)[M,K] @ Wt^T)/64 (+bias))
// Wt given as hi/lo f16 [N][ldb] (K-contiguous), pre-scaled by 64. BM=128, BK=32, 4 waves.
template<int BN, int TM, int TN, bool LN, bool PATCH, bool BIAS, bool GELU, bool RESID>
__global__ __launch_bounds__(256) void gemm_mfma(
    const float* __restrict__ A, int lda,
    const float* __restrict__ stats,
    const float* __restrict__ lng, const float* __restrict__ lnb,
    const ushort* __restrict__ wtH, const ushort* __restrict__ wtL, int ldb,
    const float* __restrict__ bias, float* __restrict__ C,
    const float* __restrict__ videos, const float* __restrict__ atok,
    int M, int N, int K)
{
  constexpr int NWC = BN / (TN * 16);
  __shared__ __align__(16) ushort sAh[128 * 40];
  __shared__ __align__(16) ushort sAl[128 * 40];
  __shared__ __align__(16) ushort sBh[BN * 40];
  __shared__ __align__(16) ushort sBl[BN * 40];
  const int tid = threadIdx.x;
  const int m0 = blockIdx.x * 128, n0 = blockIdx.y * BN;
  const int wid = tid >> 6, lane = tid & 63;
  const int lrow = lane & 15, lkg = lane >> 4;
  const int wr = wid / NWC, wc = wid % NWC;
  const int wrb = wr * TM * 16, wcb = wc * TN * 16;
  f32x4 acc[TM][TN];
#pragma unroll
  for (int mi = 0; mi < TM; mi++)
#pragma unroll
    for (int ni = 0; ni < TN; ni++) acc[mi][ni] = (f32x4){0.f, 0.f, 0.f, 0.f};

  const int rowa = tid >> 1, kba = (tid & 1) << 4;
  const int arow = m0 + rowa;
  const bool rowok = (arow < M);
  int bt_p = 0, s_p = 0;
  float mean = 0.f, rstd = 0.f;
  if (PATCH) { bt_p = arow / 257; s_p = arow - bt_p * 257; }
  else if (LN) { if (rowok) { mean = stats[2 * (long)arow]; rstd = stats[2 * (long)arow + 1]; } }
  const float* aptr = (!PATCH && rowok) ? (A + (long)arow * lda + kba) : nullptr;

  for (int k0 = 0; k0 < K; k0 += 32) {
    // ---- stage A (fp32 -> split f16 hi/lo)
    {
      float4 vr[4];
#pragma unroll
      for (int q = 0; q < 4; q++) vr[q] = make_float4(0.f, 0.f, 0.f, 0.f);
      if (PATCH) {
#pragma unroll
        for (int q = 0; q < 4; q++) {
          int e4 = k0 + kba + 4 * q;
          if (s_p == 0) {
            vr[q] = *(const float4*)(atok + e4);
          } else {
            int p = s_p - 1, ph = p >> 4, pw = p & 15;
            int iq = e4 / 24, jc = e4 - iq * 24;
            vr[q] = *(const float4*)(videos + (long)bt_p * 49152 +
                                     (long)(ph * 8 + iq) * 384 + pw * 24 + jc);
          }
        }
      } else if (rowok) {
#pragma unroll
        for (int q = 0; q < 4; q++) vr[q] = *(const float4*)(aptr + k0 + 4 * q);
        if (LN) {
#pragma unroll
          for (int q = 0; q < 4; q++) {
            float4 g4 = *(const float4*)(lng + k0 + kba + 4 * q);
            float4 b4 = *(const float4*)(lnb + k0 + kba + 4 * q);
            vr[q].x = (vr[q].x - mean) * rstd * g4.x + b4.x;
            vr[q].y = (vr[q].y - mean) * rstd * g4.y + b4.y;
            vr[q].z = (vr[q].z - mean) * rstd * g4.z + b4.z;
            vr[q].w = (vr[q].w - mean) * rstd * g4.w + b4.w;
          }
        }
      }
      uint hw[8], lw[8];
#pragma unroll
      for (int q = 0; q < 4; q++) {
        ushort h0,l0,h1,l1,h2,l2,h3,l3;
        split_f16(vr[q].x, h0, l0); split_f16(vr[q].y, h1, l1);
        split_f16(vr[q].z, h2, l2); split_f16(vr[q].w, h3, l3);
        hw[2*q]   = (uint)h0 | ((uint)h1 << 16); lw[2*q]   = (uint)l0 | ((uint)l1 << 16);
        hw[2*q+1] = (uint)h2 | ((uint)h3 << 16); lw[2*q+1] = (uint)l2 | ((uint)l3 << 16);
      }
      uint4* dh = (uint4*)&sAh[rowa * 40 + kba];
      dh[0] = make_uint4(hw[0], hw[1], hw[2], hw[3]);
      dh[1] = make_uint4(hw[4], hw[5], hw[6], hw[7]);
      uint4* dl = (uint4*)&sAl[rowa * 40 + kba];
      dl[0] = make_uint4(lw[0], lw[1], lw[2], lw[3]);
      dl[1] = make_uint4(lw[4], lw[5], lw[6], lw[7]);
    }
    // ---- stage B (pre-split f16, straight copies)
    if (BN == 128) {
      const int colb = tid >> 1, kbb = (tid & 1) << 4;
      const ushort* srch = wtH + (long)(n0 + colb) * ldb + k0 + kbb;
      const ushort* srcl = wtL + (long)(n0 + colb) * ldb + k0 + kbb;
      uint4* dh = (uint4*)&sBh[colb * 40 + kbb];
      dh[0] = ((const uint4*)srch)[0]; dh[1] = ((const uint4*)srch)[1];
      uint4* dl = (uint4*)&sBl[colb * 40 + kbb];
      dl[0] = ((const uint4*)srcl)[0]; dl[1] = ((const uint4*)srcl)[1];
    } else {
      const int colb = tid >> 2, kbb = (tid & 3) << 3;
      *(uint4*)&sBh[colb * 40 + kbb] = *(const uint4*)(wtH + (long)(n0 + colb) * ldb + k0 + kbb);
      *(uint4*)&sBl[colb * 40 + kbb] = *(const uint4*)(wtL + (long)(n0 + colb) * ldb + k0 + kbb);
    }
    __syncthreads();
    // ---- compute: 3 MFMA per fragment pair (AhBh + AhBl + AlBh), fp32 accumulate
    half8 aH[TM], aL[TM];
#pragma unroll
    for (int mi = 0; mi < TM; mi++) {
      int off = (wrb + mi * 16 + lrow) * 40 + lkg * 8;
      aH[mi] = *(const half8*)&sAh[off];
      aL[mi] = *(const half8*)&sAl[off];
    }
#pragma unroll
    for (int ni = 0; ni < TN; ni++) {
      int off = (wcb + ni * 16 + lrow) * 40 + lkg * 8;
      half8 bH = *(const half8*)&sBh[off];
      half8 bL = *(const half8*)&sBl[off];
#pragma unroll
      for (int mi = 0; mi < TM; mi++) {
        acc[mi][ni] = __builtin_amdgcn_mfma_f32_16x16x32_f16(aL[mi], bH, acc[mi][ni], 0, 0, 0);
        acc[mi][ni] = __builtin_amdgcn_mfma_f32_16x16x32_f16(aH[mi], bL, acc[mi][ni], 0, 0, 0);
        acc[mi][ni] = __builtin_amdgcn_mfma_f32_16x16x32_f16(aH[mi], bH, acc[mi][ni], 0, 0, 0);
      }
    }
    __syncthreads();
  }
  // ---- epilogue (unscale by 1/64, then bias/act/resid)
#pragma unroll
  for (int mi = 0; mi < TM; mi++) {
    int rowg = m0 + wrb + mi * 16 + lkg * 4;
#pragma unroll
    for (int j = 0; j < 4; j++) {
      int r = rowg + j;
      if (r < M) {
#pragma unroll
        for (int ni = 0; ni < TN; ni++) {
          int cg = n0 + wcb + ni * 16 + lrow;
          float v = acc[mi][ni][j] * WINV;
          if (BIAS) v += bias[cg];
          if (GELU) v = gelu_f(v);
          long idx = (long)r * N + cg;
          if (RESID) C[idx] += v; else C[idx] = v;
        }
      }
    }
  }
}

// ---------------- spatial attention (fp32): scores for 64 (frame,head) pairs of a chunk
__global__ __launch_bounds__(256) void spatial_scores(
    const float* __restrict__ qkvc, float* __restrict__ scores, int fh_base)
{
  const int fh = fh_base + blockIdx.z;
  const int fl = fh >> 3, hh = fh & 7;
  const float* Q  = qkvc + (long)fl * S_ * 1536 + hh * HD_;
  const float* Kp = Q + 512;
  float* Cm = scores + (long)blockIdx.z * S_ * S_;
  const int m0 = blockIdx.x << 6, n0 = blockIdx.y << 6;
  __shared__ __align__(16) float Qs[16][68];
  __shared__ __align__(16) float Ks[16][68];
  const int tid = threadIdx.x, tx = tid & 15, ty = tid >> 4;
  const int lr = tid >> 2, lc = (tid & 3) << 2;
  float acc[4][4] = {};
  for (int k0 = 0; k0 < 64; k0 += 16) {
    float4 qv = make_float4(0,0,0,0), kv = make_float4(0,0,0,0);
    if (m0 + lr < S_) qv = *(const float4*)(Q  + (long)(m0 + lr) * 1536 + k0 + lc);
    if (n0 + lr < S_) kv = *(const float4*)(Kp + (long)(n0 + lr) * 1536 + k0 + lc);
    Qs[lc+0][lr]=qv.x; Qs[lc+1][lr]=qv.y; Qs[lc+2][lr]=qv.z; Qs[lc+3][lr]=qv.w;
    Ks[lc+0][lr]=kv.x; Ks[lc+1][lr]=kv.y; Ks[lc+2][lr]=kv.z; Ks[lc+3][lr]=kv.w;
    __syncthreads();
#pragma unroll
    for (int kk = 0; kk < 16; kk++) {
      const float4 a4 = *(const float4*)&Qs[kk][ty << 2];
      const float4 b4 = *(const float4*)&Ks[kk][tx << 2];
      const float a_[4] = {a4.x, a4.y, a4.z, a4.w};
      const float b_[4] = {b4.x, b4.y, b4.z, b4.w};
#pragma unroll
      for (int i = 0; i < 4; i++)
#pragma unroll
        for (int j = 0; j < 4; j++)
          acc[i][j] = fmaf(a_[i], b_[j], acc[i][j]);
    }
    __syncthreads();
  }
#pragma unroll
  for (int i = 0; i < 4; i++) {
    int m = m0 + (ty << 2) + i;
    if (m >= S_) continue;
#pragma unroll
    for (int j = 0; j < 4; j++) {
      int n = n0 + (tx << 2) + j;
      if (n < S_) Cm[(long)m * S_ + n] = acc[i][j] * 0.125f;
    }
  }
}

__global__ __launch_bounds__(256) void softmax_rows(float* __restrict__ sc)
{
  int row = blockIdx.x * 4 + (threadIdx.x >> 6);
  int lane = threadIdx.x & 63;
  float* p = sc + (long)row * S_;
  float v[5]; float mx = -3.0e38f;
#pragma unroll
  for (int j = 0; j < 5; j++) {
    int idx = lane + (j << 6);
    v[j] = (idx < S_) ? p[idx] : -3.0e38f;
    mx = fmaxf(mx, v[j]);
  }
  mx = warp_rmax(mx);
  float sum = 0.f;
#pragma unroll
  for (int j = 0; j < 5; j++) {
    int idx = lane + (j << 6);
    float e = (idx < S_) ? expf(v[j] - mx) : 0.f;
    v[j] = e; sum += e;
  }
  sum = warp_rsum(sum);
  float inv = 1.0f / sum;
#pragma unroll
  for (int j = 0; j < 5; j++) {
    int idx = lane + (j << 6);
    if (idx < S_) p[idx] = v[j] * inv;
  }
}

__global__ __launch_bounds__(256) void spatial_pv(
    const float* __restrict__ qkvc, const float* __restrict__ scores,
    float* __restrict__ ctxc, int fh_base)
{
  const int fh = fh_base + blockIdx.z;
  const int fl = fh >> 3, hh = fh & 7;
  const float* P = scores + (long)blockIdx.z * S_ * S_;
  const float* V = qkvc + (long)fl * S_ * 1536 + 1024 + hh * HD_;
  float* Cm = ctxc + (long)fl * S_ * D_ + hh * HD_;
  const int m0 = blockIdx.x << 6;
  __shared__ __align__(16) float Ps[16][68];
  __shared__ __align__(16) float Vs[16][64];
  const int tid = threadIdx.x, tx = tid & 15, ty = tid >> 4;
  const int lr = tid >> 2, lc = (tid & 3) << 2;
  const int br = tid >> 4, bc = (tid & 15) << 2;
  float acc[4][4] = {};
  for (int k0 = 0; k0 < S_; k0 += 16) {
#pragma unroll
    for (int e = 0; e < 4; e++) {
      int kcol = k0 + lc + e;
      Ps[lc+e][lr] = (m0 + lr < S_ && kcol < S_) ? P[(long)(m0 + lr) * S_ + kcol] : 0.f;
    }
    int vrr = k0 + br;
    float4 vv = make_float4(0,0,0,0);
    if (vrr < S_) vv = *(const float4*)(V + (long)vrr * 1536 + bc);
    *(float4*)&Vs[br][bc] = vv;
    __syncthreads();
#pragma unroll
    for (int kk = 0; kk < 16; kk++) {
      const float4 a4 = *(const float4*)&Ps[kk][ty << 2];
      const float4 b4 = *(const float4*)&Vs[kk][tx << 2];
      const float a_[4] = {a4.x, a4.y, a4.z, a4.w};
      const float b_[4] = {b4.x, b4.y, b4.z, b4.w};
#pragma unroll
      for (int i = 0; i < 4; i++)
#pragma unroll
        for (int j = 0; j < 4; j++)
          acc[i][j] = fmaf(a_[i], b_[j], acc[i][j]);
    }
    __syncthreads();
  }
#pragma unroll
  for (int i = 0; i < 4; i++) {
    int m = m0 + (ty << 2) + i;
    if (m >= S_) continue;
#pragma unroll
    for (int j = 0; j < 4; j++) {
      int n = (tx << 2) + j;
      Cm[(long)m * D_ + n] = acc[i][j];
    }
  }
}

// ---------------- temporal causal attention for one batch chunk (rows t*257+s)
__global__ __launch_bounds__(64) void temporal_attn(
    const float* __restrict__ qkvc, float* __restrict__ ctxc)
{
  const int gid = blockIdx.x;           // s*8+h
  const int hh = gid & 7;
  const int s = gid >> 3;
  const int lane = threadIdx.x;
  __shared__ float Qs[16][65];
  __shared__ float Ks[16][65];
  __shared__ float Pm[16][17];
  float v[16];
  const long base = (long)s * 1536 + hh * HD_ + lane;
  const long tstr = (long)S_ * 1536;
#pragma unroll
  for (int t = 0; t < 16; t++) {
    long r = base + t * tstr;
    Qs[t][lane] = qkvc[r];
    Ks[t][lane] = qkvc[r + 512];
    v[t] = qkvc[r + 1024];
  }
  __syncthreads();
  const int rq = lane >> 2, c0 = lane & 3;
  float sc[4];
#pragma unroll
  for (int j = 0; j < 4; j++) {
    int c = c0 + (j << 2);
    if (c <= rq) {
      float d = 0.f;
#pragma unroll
      for (int k = 0; k < 64; k++) d = fmaf(Qs[rq][k], Ks[c][k], d);
      sc[j] = d * 0.125f;
    } else sc[j] = -3.0e38f;
  }
  float mx = fmaxf(fmaxf(sc[0], sc[1]), fmaxf(sc[2], sc[3]));
  mx = fmaxf(mx, __shfl_xor(mx, 1));
  mx = fmaxf(mx, __shfl_xor(mx, 2));
  float sum = 0.f;
#pragma unroll
  for (int j = 0; j < 4; j++) { sc[j] = expf(sc[j] - mx); sum += sc[j]; }
  sum += __shfl_xor(sum, 1);
  sum += __shfl_xor(sum, 2);
  float inv = 1.0f / sum;
#pragma unroll
  for (int j = 0; j < 4; j++) Pm[rq][c0 + (j << 2)] = sc[j] * inv;
  __syncthreads();
#pragma unroll
  for (int t = 0; t < 16; t++) {
    float o = 0.f;
#pragma unroll
    for (int k = 0; k < 16; k++) o = fmaf(Pm[t][k], v[k], o);
    ctxc[((long)t * S_ + s) * D_ + hh * HD_ + lane] = o;
  }
}

// ---------------- final LN + projection + VQ argmin + action head
__global__ __launch_bounds__(256) void final_vq(
    const float* __restrict__ tok, const float* __restrict__ lnf_g,
    const float* __restrict__ lnf_b, const float* __restrict__ out_w,
    const float* __restrict__ codebook, const float* __restrict__ action_w,
    float* __restrict__ out)
{
  __shared__ float xs[512];
  __shared__ float red[256];
  __shared__ float zs[64];
  __shared__ float bd[256];
  __shared__ int   bi[256];
  const int b = blockIdx.x / 15, tm = blockIdx.x % 15;
  const int tid = threadIdx.x;
  const float* xr = tok + ((long)(b * T_ + tm + 1) * S_) * D_;   // s = 0
  xs[tid] = xr[tid]; xs[tid + 256] = xr[tid + 256];
  red[tid] = xs[tid] + xs[tid + 256];
  __syncthreads();
  for (int off = 128; off >= 1; off >>= 1) {
    if (tid < off) red[tid] += red[tid + off];
    __syncthreads();
  }
  float mean = red[0] * (1.0f / 512.0f);
  __syncthreads();
  float d0 = xs[tid] - mean, d1 = xs[tid + 256] - mean;
  red[tid] = d0 * d0 + d1 * d1;
  __syncthreads();
  for (int off = 128; off >= 1; off >>= 1) {
    if (tid < off) red[tid] += red[tid + off];
    __syncthreads();
  }
  float rs = rsqrtf(red[0] * (1.0f / 512.0f) + 1e-5f);
  __syncthreads();
  xs[tid]       = d0 * rs * lnf_g[tid]       + lnf_b[tid];
  xs[tid + 256] = d1 * rs * lnf_g[tid + 256] + lnf_b[tid + 256];
  __syncthreads();
  if (tid < 64) {
    float z = 0.f;
    for (int d = 0; d < 512; d++) z = fmaf(xs[d], out_w[d * 64 + tid], z);
    zs[tid] = z;
  }
  __syncthreads();
  float best = 3.0e38f; int bidx = 0;
  for (int c = tid; c < 4096; c += 256) {
    const float* cp = codebook + (long)c * 64;
    float dot = 0.f, cn = 0.f;
#pragma unroll 8
    for (int k = 0; k < 64; k++) { float w = cp[k]; dot = fmaf(zs[k], w, dot); cn = fmaf(w, w, cn); }
    float dist = cn - 2.0f * dot;
    if (dist < best) { best = dist; bidx = c; }
  }
  bd[tid] = best; bi[tid] = bidx;
  __syncthreads();
  for (int off = 128; off >= 1; off >>= 1) {
    if (tid < off) {
      if (bd[tid + off] < bd[tid] || (bd[tid + off] == bd[tid] && bi[tid + off] < bi[tid])) {
        bd[tid] = bd[tid + off]; bi[tid] = bi[tid + off];
      }
    }
    __syncthreads();
  }
  int idx = bi[0];
  if (tid < 16) {
    const float* cp = codebook + (long)idx * 64;
    float o = 0.f;
#pragma unroll
    for (int k = 0; k < 64; k++) o = fmaf(cp[k], action_w[k * 16 + tid], o);
    out[((long)(b * 15 + tm)) * 16 + tid] = o;
  }
}

extern "C" void kernel_launch(void* const* d_in, const int* in_sizes, int n_in,
                              void* d_out, int out_size, void* d_ws, size_t ws_size,
                              hipStream_t stream)
{
  const float* videos       = (const float*)d_in[0];
  const float* patch_w      = (const float*)d_in[1];
  const float* patch_b      = (const float*)d_in[2];
  const float* action_token = (const float*)d_in[3];
  const float* ln1_g  = (const float*)d_in[4];
  const float* ln1_b  = (const float*)d_in[5];
  const float* wqkv_s = (const float*)d_in[6];
  const float* wo_s   = (const float*)d_in[7];
  const float* ln2_g  = (const float*)d_in[8];
  const float* ln2_b  = (const float*)d_in[9];
  const float* wqkv_t = (const float*)d_in[10];
  const float* wo_t   = (const float*)d_in[11];
  const float* ln3_g  = (const float*)d_in[12];
  const float* ln3_b  = (const float*)d_in[13];
  const float* mlp_w1 = (const float*)d_in[14];
  const float* mlp_b1 = (const float*)d_in[15];
  const float* mlp_w2 = (const float*)d_in[16];
  const float* mlp_b2 = (const float*)d_in[17];
  const float* lnf_g  = (const float*)d_in[18];
  const float* lnf_b  = (const float*)d_in[19];
  const float* out_w  = (const float*)d_in[20];
  const float* codebook = (const float*)d_in[21];
  const float* action_w = (const float*)d_in[22];
  float* out = (float*)d_out;

  // ---- workspace layout (floats), total 33,759,552 = 135.04 MB
  float* ws    = (float*)d_ws;
  float* tok   = ws;                                  // 16,842,752
  float* stats = ws + 16842752;                       //     65,792
  ushort* wt1h = (ushort*)(ws + 16908544);            //  1,048,576 f32-equiv (hi+lo)
  ushort* wt1l = wt1h + 1048576;
  ushort* wt2h = (ushort*)(ws + 17957120);            //  1,048,576 f32-equiv
  ushort* wt2l = wt2h + 1048576;
  float* qkvc  = ws + 19005696;                       //  6,316,032  (4112 x 1536)
  float* ctxc  = ws + 25321728;                       //  2 x 2,105,344 (chunk pair)
  float* scratch = ws + 29532416;                     //  4,227,136  (scores 64 fh)
  float* mid   = ctxc;                                //  ctxc+scratch union: 8,437,824 >= 4096*2048

  // ---- patchify fused into embed GEMM; patch_w [192][512] -> wt1
  convert_w<<<dim3(3, 8), 256, 0, stream>>>(patch_w, wt1h, wt1l, 512, 192);
  gemm_mfma<128,4,4,false,true,true,false,false><<<dim3(257, 4), 256, 0, stream>>>(
      nullptr, 0, nullptr, nullptr, nullptr, wt1h, wt1l, 192, patch_b, tok,
      videos, action_token, NTOK, 512, 192);

  for (int L = 0; L < 4; L++) {
    // ================= spatial attention =================
    convert_w<<<dim3(8, 24), 256, 0, stream>>>(wqkv_s + (long)L*512*1536, wt1h, wt1l, 1536, 512);
    convert_w<<<dim3(8, 8),  256, 0, stream>>>(wo_s   + (long)L*512*512,  wt2h, wt2l, 512, 512);
    ln_stats<<<NTOK / 4, 256, 0, stream>>>(tok, stats);
    for (int p = 0; p < 4; p++) {
      for (int ci = 0; ci < 2; ci++) {
        long r0 = (long)(2 * p + ci) * CH;
        gemm_mfma<128,4,4,true,false,false,false,false><<<dim3(33, 12), 256, 0, stream>>>(
            tok + r0 * D_, D_, stats + r0 * 2, ln1_g + L*512, ln1_b + L*512,
            wt1h, wt1l, 512, nullptr, qkvc, nullptr, nullptr, CH, 1536, 512);
        for (int hf = 0; hf < 2; hf++) {
          spatial_scores<<<dim3(5, 5, 64), 256, 0, stream>>>(qkvc, scratch, hf * 64);
          softmax_rows<<<(64 * S_) / 4, 256, 0, stream>>>(scratch);
          spatial_pv<<<dim3(5, 1, 64), 256, 0, stream>>>(qkvc, scratch, ctxc + (long)ci*CH*D_, hf * 64);
        }
      }
      gemm_mfma<64,2,4,false,false,false,false,true><<<dim3(65, 8), 256, 0, stream>>>(
          ctxc, D_, nullptr, nullptr, nullptr, wt2h, wt2l, 512, nullptr,
          tok + (long)p * 2 * CH * D_, nullptr, nullptr, 2 * CH, 512, 512);
    }
    // ================= temporal attention =================
    convert_w<<<dim3(8, 24), 256, 0, stream>>>(wqkv_t + (long)L*512*1536, wt1h, wt1l, 1536, 512);
    convert_w<<<dim3(8, 8),  256, 0, stream>>>(wo_t   + (long)L*512*512,  wt2h, wt2l, 512, 512);
    ln_stats<<<NTOK / 4, 256, 0, stream>>>(tok, stats);
    for (int p = 0; p < 4; p++) {
      for (int ci = 0; ci < 2; ci++) {
        long r0 = (long)(2 * p + ci) * CH;
        gemm_mfma<128,4,4,true,false,false,false,false><<<dim3(33, 12), 256, 0, stream>>>(
            tok + r0 * D_, D_, stats + r0 * 2, ln2_g + L*512, ln2_b + L*512,
            wt1h, wt1l, 512, nullptr, qkvc, nullptr, nullptr, CH, 1536, 512);
        temporal_attn<<<S_ * NH_, 64, 0, stream>>>(qkvc, ctxc + (long)ci*CH*D_);
      }
      gemm_mfma<64,2,4,false,false,false,false,true><<<dim3(65, 8), 256, 0, stream>>>(
          ctxc, D_, nullptr, nullptr, nullptr, wt2h, wt2l, 512, nullptr,
          tok + (long)p * 2 * CH * D_, nullptr, nullptr, 2 * CH, 512, 512);
    }
    // ================= MLP (M-chunks of 4096 rows; LN read-before-write per chunk) ======
    convert_w<<<dim3(8, 32), 256, 0, stream>>>(mlp_w1 + (long)L*512*2048, wt1h, wt1l, 2048, 512);
    convert_w<<<dim3(32, 8), 256, 0, stream>>>(mlp_w2 + (long)L*2048*512, wt2h, wt2l, 512, 2048);
    ln_stats<<<NTOK / 4, 256, 0, stream>>>(tok, stats);
    for (int c = 0; c < 9; c++) {
      long m0r = (long)c * 4096;
      int mr = NTOK - (int)m0r; if (mr > 4096) mr = 4096;
      if (mr <= 0) break;
      gemm_mfma<128,4,4,true,false,true,true,false><<<dim3((mr + 127) / 128, 16), 256, 0, stream>>>(
          tok + m0r * D_, D_, stats + m0r * 2, ln3_g + L*512, ln3_b + L*512,
          wt1h, wt1l, 512, mlp_b1 + (long)L*2048, mid, nullptr, nullptr, mr, FFN_, 512);
      gemm_mfma<64,2,4,false,false,true,false,true><<<dim3((mr + 127) / 128, 8), 256, 0, stream>>>(
          mid, FFN_, nullptr, nullptr, nullptr, wt2h, wt2l, 2048,
          mlp_b2 + (long)L*512, tok + m0r * D_, nullptr, nullptr, mr, 512, 2048);
    }
  }

  final_vq<<<B_ * (T_ - 1), 256, 0, stream>>>(tok, lnf_g, lnf_b, out_w, codebook, action_w, out);
}